// Round 2
// baseline (216.766 us; speedup 1.0000x reference)
//
#include <hip/hip_runtime.h>

#define EPS 1e-5f
#define PROJ_EPS 1e-5f
#define MAX_TANH_ARG 15.0f

typedef __bf16 bf16x8 __attribute__((ext_vector_type(8)));
typedef float f32x4 __attribute__((ext_vector_type(4)));
typedef float f32x2 __attribute__((ext_vector_type(2)));

__device__ __forceinline__ unsigned short f2bf(float f) {
  unsigned u = __builtin_bit_cast(unsigned, f);
  u += 0x7fffu + ((u >> 16) & 1u);   // round-to-nearest-even
  return (unsigned short)(u >> 16);
}
__device__ __forceinline__ float bf2f(unsigned short h) {
  return __builtin_bit_cast(float, ((unsigned)h) << 16);
}

union BF8 {
  unsigned short u[8];
  bf16x8 v;
  uint4 q;
};

// ---------------------------------------------------------------------------
// Pack W[layer][k][n] (fp32) into bf16 B-fragment order for 16x16x32 MFMA.
// ---------------------------------------------------------------------------
__global__ void pack_w_kernel(const float* __restrict__ W,
                              unsigned short* __restrict__ wpack) {
  int tid = blockIdx.x * blockDim.x + threadIdx.x;  // 0..4095
  if (tid >= 2 * 8 * 4 * 64) return;
  int lane = tid & 63;
  int s = (tid >> 6) & 3;
  int t = (tid >> 8) & 7;
  int layer = tid >> 11;
  int quad = lane >> 4;
  int n = t * 16 + (lane & 15);
  unsigned short* dst = wpack + ((size_t)((layer * 32 + t * 4 + s) * 64 + lane)) * 8;
  const float* src = W + (size_t)layer * 16384;
#pragma unroll
  for (int j = 0; j < 8; ++j) {
    int k = s * 32 + quad * 8 + j;
    dst[j] = f2bf(src[(size_t)k * 128 + n]);
  }
}

// ---------------------------------------------------------------------------
// msg[row,:] = rowscale_eff[row] * (x[row,:] @ W) via mfma_f32_16x16x32_bf16.
// MODE 0: x = fp32 node_repr, eff scale = mask[row]^2.
// MODE 1: x = bf16 x1,        eff scale = lsp[row] (precomputed ls*mask^2).
// Block = 256 thr = 4 waves; wave does 16 rows x 128 cols. Epilogue stages the
// 64x128 bf16 C tile in LDS, then stores coalesced dwordx4 (4 KB/wave/inst).
// ---------------------------------------------------------------------------
template <int MODE>
__global__ __launch_bounds__(256) void gemm_kernel(
    const float* __restrict__ xf, const unsigned short* __restrict__ xb,
    const float* __restrict__ rowscale, const unsigned short* __restrict__ wpack,
    unsigned short* __restrict__ msg, int N) {
  __shared__ unsigned short tile[64][136];  // 136: stride 272B, 16B-aligned rows
  const int lane = threadIdx.x & 63;
  const int wv = threadIdx.x >> 6;
  const int m = lane & 15;
  const int quad = lane >> 4;
  const int base = blockIdx.x * 64;
  const int wbase = base + wv * 16;
  const int row = wbase + m;
  const int rowc = row < N ? row : N - 1;

  f32x4 acc[8];
#pragma unroll
  for (int t = 0; t < 8; ++t) acc[t] = (f32x4){0.f, 0.f, 0.f, 0.f};

#pragma unroll
  for (int sk = 0; sk < 4; ++sk) {
    const int k0 = sk * 32 + quad * 8;
    BF8 a;
    if (MODE == 0) {
      const float4* xp = (const float4*)(xf + (size_t)rowc * 128 + k0);
      float4 p0 = xp[0], p1 = xp[1];
      a.u[0] = f2bf(p0.x); a.u[1] = f2bf(p0.y);
      a.u[2] = f2bf(p0.z); a.u[3] = f2bf(p0.w);
      a.u[4] = f2bf(p1.x); a.u[5] = f2bf(p1.y);
      a.u[6] = f2bf(p1.z); a.u[7] = f2bf(p1.w);
    } else {
      a.q = *(const uint4*)(xb + (size_t)rowc * 128 + k0);
    }
#pragma unroll
    for (int t = 0; t < 8; ++t) {
      BF8 b;
      b.q = *(const uint4*)(wpack + (size_t)((t * 4 + sk) * 64 + lane) * 8);
      acc[t] = __builtin_amdgcn_mfma_f32_16x16x32_bf16(a.v, b.v, acc[t], 0, 0, 0);
    }
  }

  // Row scale: C/D layout row = quad*4 + r (within the wave's 16 rows)
  float sc[4];
#pragma unroll
  for (int r = 0; r < 4; ++r) {
    int rr = wbase + quad * 4 + r;
    rr = rr < N ? rr : N - 1;
    float s = rowscale[rr];
    sc[r] = (MODE == 0) ? s * s : s;
  }
#pragma unroll
  for (int t = 0; t < 8; ++t) {
    const int c = t * 16 + m;
#pragma unroll
    for (int r = 0; r < 4; ++r) {
      tile[wv * 16 + quad * 4 + r][c] = f2bf(acc[t][r] * sc[r]);
    }
  }
  __syncthreads();

  // Coalesced write-out: 256 threads cover the 16 KB tile in 4 dwordx4 each.
#pragma unroll
  for (int i = 0; i < 4; ++i) {
    const int flat = i * 4096 + (int)threadIdx.x * 16;  // byte offset in tile
    const int r64 = flat >> 8;
    const int colb = flat & 255;
    const int grow = base + r64;
    if (grow < N) {
      *(uint4*)((char*)msg + (size_t)grow * 256 + colb) =
          *(const uint4*)&tile[r64][colb >> 1];
    }
  }
}

// ---------------------------------------------------------------------------
// Per node n: c = sum_k w[n,k]*msg[adj[n,k],:]; x = relu(expmap0(c*m)*m)*m.
// Two nodes per wave (64 loads in flight); neighbor idx/weight broadcast via
// readlane -> SGPR addressing; packed v_pk_fma_f32 accumulation.
// MODE 0: store bf16 x1 + folded log-map scale lsp[n] = ls*mask^2.
// MODE 1: store fp32 out.
// ---------------------------------------------------------------------------
template <int MODE>
__global__ __launch_bounds__(256) void gather_kernel(
    const unsigned short* __restrict__ msg, const int* __restrict__ adj,
    const float* __restrict__ wgt, const float* __restrict__ mask,
    unsigned short* __restrict__ x1out, float* __restrict__ lsout,
    float* __restrict__ out, int N) {
  const int lane = threadIdx.x & 63;
  const int half = lane >> 5;
  const int j = lane & 31;
  const int gw = (int)((blockIdx.x * blockDim.x + threadIdx.x) >> 6);
  const int nw = (int)((gridDim.x * blockDim.x) >> 6);
  const int npairs = (N + 1) >> 1;

  for (int p = gw; p < npairs; p += nw) {
    const int nA = p * 2;
    const int nB = nA + 1;
    const int myn = nA + half;
    int idxv = 0;
    float wv = 0.f;
    if (myn < N) {
      idxv = adj[(size_t)myn * 32 + j];
      wv = wgt[(size_t)myn * 32 + j];
    }
    f32x2 aA = {0.f, 0.f}, aB = {0.f, 0.f};
#pragma unroll
    for (int k = 0; k < 32; ++k) {
      const int idA = __builtin_amdgcn_readlane(idxv, k);
      const float wA = __builtin_bit_cast(
          float, __builtin_amdgcn_readlane(__builtin_bit_cast(int, wv), k));
      const int idB = __builtin_amdgcn_readlane(idxv, 32 + k);
      const float wB = __builtin_bit_cast(
          float, __builtin_amdgcn_readlane(__builtin_bit_cast(int, wv), 32 + k));
      const unsigned prA = *(const unsigned*)(msg + (size_t)idA * 128 + 2 * lane);
      const unsigned prB = *(const unsigned*)(msg + (size_t)idB * 128 + 2 * lane);
      f32x2 mA, mB;
      mA.x = __builtin_bit_cast(float, prA << 16);
      mA.y = __builtin_bit_cast(float, prA & 0xffff0000u);
      mB.x = __builtin_bit_cast(float, prB << 16);
      mB.y = __builtin_bit_cast(float, prB & 0xffff0000u);
      aA = __builtin_elementwise_fma(mA, (f32x2){wA, wA}, aA);
      aB = __builtin_elementwise_fma(mB, (f32x2){wB, wB}, aB);
    }

#pragma unroll
    for (int which = 0; which < 2; ++which) {
      const int n = which ? nB : nA;
      if (n >= N) continue;
      const f32x2 a = which ? aB : aA;
      const float mm = mask[n];
      const float c0 = a.x * mm, c1 = a.y * mm;
      float s2 = c0 * c0 + c1 * c1;
#pragma unroll
      for (int o = 32; o > 0; o >>= 1) s2 += __shfl_xor(s2, o);
      const float nrm = sqrtf(s2);
      const float ncl = fminf(fmaxf(nrm, EPS), MAX_TANH_ARG);
      const float esc = tanhf(ncl) / fmaxf(nrm, EPS) * mm;
      const float v0 = fmaxf(esc * c0, 0.f) * mm;
      const float v1 = fmaxf(esc * c1, 0.f) * mm;
      if (MODE == 0) {
        const unsigned pk = (unsigned)f2bf(v0) | ((unsigned)f2bf(v1) << 16);
        *(unsigned*)(x1out + (size_t)n * 128 + 2 * lane) = pk;
        float r2 = v0 * v0 + v1 * v1;
#pragma unroll
        for (int o = 32; o > 0; o >>= 1) r2 += __shfl_xor(r2, o);
        const float nr = sqrtf(r2);
        const float nc2 = fminf(fmaxf(nr, EPS), 1.0f - PROJ_EPS);
        const float ls = 0.5f * logf((1.0f + nc2) / (1.0f - nc2)) / fmaxf(nr, EPS);
        if (lane == 0) lsout[n] = ls * mm * mm;  // fold next-layer mask^2
      } else {
        *(float2*)(out + (size_t)n * 128 + 2 * lane) = make_float2(v0, v1);
      }
    }
  }
}

extern "C" void kernel_launch(void* const* d_in, const int* in_sizes, int n_in,
                              void* d_out, int out_size, void* d_ws, size_t ws_size,
                              hipStream_t stream) {
  const float* node = (const float*)d_in[0];        // [N,128] fp32
  const int* adj = (const int*)d_in[1];             // [N,32] int32
  const float* wgt = (const float*)d_in[2];         // [N,32] fp32
  const float* mask = (const float*)d_in[3];        // [N,1] fp32
  const float* mw = (const float*)d_in[4];          // [2,128,128] fp32
  float* out = (float*)d_out;
  const int N = in_sizes[0] / 128;

  // workspace: wpack (64 KiB) | lsp (N fp32, 256B-aligned) | msg (N*128 bf16)
  char* ws = (char*)d_ws;
  unsigned short* wpack = (unsigned short*)ws;
  float* lsp = (float*)(ws + 65536);
  size_t ls_bytes = ((size_t)N * 4 + 255) & ~(size_t)255;
  unsigned short* msg = (unsigned short*)(ws + 65536 + ls_bytes);
  // x1 (bf16, N*128 = half of d_out) lives in d_out; dead before final write
  unsigned short* x1 = (unsigned short*)d_out;

  hipLaunchKernelGGL(pack_w_kernel, dim3(16), dim3(256), 0, stream, mw, wpack);
  const int gb = (N + 63) / 64;
  hipLaunchKernelGGL((gemm_kernel<0>), dim3(gb), dim3(256), 0, stream,
                     node, (const unsigned short*)nullptr, mask, wpack, msg, N);
  hipLaunchKernelGGL((gather_kernel<0>), dim3(2048), dim3(256), 0, stream,
                     msg, adj, wgt, mask, x1, lsp, (float*)nullptr, N);
  hipLaunchKernelGGL((gemm_kernel<1>), dim3(gb), dim3(256), 0, stream,
                     (const float*)nullptr, x1, lsp, wpack + 16384, msg, N);
  hipLaunchKernelGGL((gather_kernel<1>), dim3(2048), dim3(256), 0, stream,
                     msg, adj, wgt, mask, (unsigned short*)nullptr, (float*)nullptr, out, N);
}

// Round 3
// 213.450 us; speedup vs baseline: 1.0155x; 1.0155x over previous
//
#include <hip/hip_runtime.h>

#define EPS 1e-5f
#define PROJ_EPS 1e-5f
#define MAX_TANH_ARG 15.0f

typedef __bf16 bf16x8 __attribute__((ext_vector_type(8)));
typedef float f32x4 __attribute__((ext_vector_type(4)));
typedef float f32x2 __attribute__((ext_vector_type(2)));

__device__ __forceinline__ unsigned short f2bf(float f) {
  unsigned u = __builtin_bit_cast(unsigned, f);
  u += 0x7fffu + ((u >> 16) & 1u);   // round-to-nearest-even
  return (unsigned short)(u >> 16);
}

union BF8 {
  unsigned short u[8];
  bf16x8 v;
  uint4 q;
};

// ---------------------------------------------------------------------------
// Pack W[layer][k][n] (fp32) into bf16 B-fragment order for 16x16x32 MFMA.
// ---------------------------------------------------------------------------
__global__ void pack_w_kernel(const float* __restrict__ W,
                              unsigned short* __restrict__ wpack) {
  int tid = blockIdx.x * blockDim.x + threadIdx.x;  // 0..4095
  if (tid >= 2 * 8 * 4 * 64) return;
  int lane = tid & 63;
  int s = (tid >> 6) & 3;
  int t = (tid >> 8) & 7;
  int layer = tid >> 11;
  int quad = lane >> 4;
  int n = t * 16 + (lane & 15);
  unsigned short* dst = wpack + ((size_t)((layer * 32 + t * 4 + s) * 64 + lane)) * 8;
  const float* src = W + (size_t)layer * 16384;
#pragma unroll
  for (int j = 0; j < 8; ++j) {
    int k = s * 32 + quad * 8 + j;
    dst[j] = f2bf(src[(size_t)k * 128 + n]);
  }
}

// ---------------------------------------------------------------------------
// msg4[plane p][row][32 cols] = rowscale * (x @ W), column-tiled bf16 output:
// plane p holds cols 32p..32p+32 (64 B per row per plane, 3.2 MB per plane ->
// per-XCD-L2-resident during each gather pass).
// MODE 0: x = fp32 node_repr, eff scale = mask^2. MODE 1: x = bf16 x1, scale = lsp.
// ---------------------------------------------------------------------------
template <int MODE>
__global__ __launch_bounds__(256) void gemm_kernel(
    const float* __restrict__ xf, const unsigned short* __restrict__ xb,
    const float* __restrict__ rowscale, const unsigned short* __restrict__ wpack,
    unsigned short* __restrict__ msg4, int N, int planeBytes) {
  __shared__ unsigned short tile[64][136];
  const int lane = threadIdx.x & 63;
  const int wv = threadIdx.x >> 6;
  const int m = lane & 15;
  const int quad = lane >> 4;
  const int base = blockIdx.x * 64;
  const int wbase = base + wv * 16;
  const int row = wbase + m;
  const int rowc = row < N ? row : N - 1;

  f32x4 acc[8];
#pragma unroll
  for (int t = 0; t < 8; ++t) acc[t] = (f32x4){0.f, 0.f, 0.f, 0.f};

#pragma unroll
  for (int sk = 0; sk < 4; ++sk) {
    const int k0 = sk * 32 + quad * 8;
    BF8 a;
    if (MODE == 0) {
      const float4* xp = (const float4*)(xf + (size_t)rowc * 128 + k0);
      float4 p0 = xp[0], p1 = xp[1];
      a.u[0] = f2bf(p0.x); a.u[1] = f2bf(p0.y);
      a.u[2] = f2bf(p0.z); a.u[3] = f2bf(p0.w);
      a.u[4] = f2bf(p1.x); a.u[5] = f2bf(p1.y);
      a.u[6] = f2bf(p1.z); a.u[7] = f2bf(p1.w);
    } else {
      a.q = *(const uint4*)(xb + (size_t)rowc * 128 + k0);
    }
#pragma unroll
    for (int t = 0; t < 8; ++t) {
      BF8 b;
      b.q = *(const uint4*)(wpack + (size_t)((t * 4 + sk) * 64 + lane) * 8);
      acc[t] = __builtin_amdgcn_mfma_f32_16x16x32_bf16(a.v, b.v, acc[t], 0, 0, 0);
    }
  }

  float sc[4];
#pragma unroll
  for (int r = 0; r < 4; ++r) {
    int rr = wbase + quad * 4 + r;
    rr = rr < N ? rr : N - 1;
    float s = rowscale[rr];
    sc[r] = (MODE == 0) ? s * s : s;
  }
#pragma unroll
  for (int t = 0; t < 8; ++t) {
    const int c = t * 16 + m;
#pragma unroll
    for (int r = 0; r < 4; ++r) {
      tile[wv * 16 + quad * 4 + r][c] = f2bf(acc[t][r] * sc[r]);
    }
  }
  __syncthreads();

  // Coalesced column-tiled write-out: plane = colb>>6, 64 B row chunks.
#pragma unroll
  for (int i = 0; i < 4; ++i) {
    const int flat = i * 4096 + (int)threadIdx.x * 16;  // byte offset in tile
    const int r64 = flat >> 8;
    const int colb = flat & 255;
    const int grow = base + r64;
    if (grow < N) {
      const int plane = colb >> 6;
      const int within = colb & 63;
      *(uint4*)((char*)msg4 + (size_t)plane * planeBytes + (size_t)grow * 64 + within) =
          *(const uint4*)&tile[r64][colb >> 1];
    }
  }
}

// ---------------------------------------------------------------------------
// Gather: block owns 64 nodes; wave owns 16 (lane: g=lane>>2 node, sub=lane&3
// 8-col sub-chunk). 4 column passes (outer) over L2-resident 3.2 MB planes;
// accumulators live in registers across passes. (id,w) staged in LDS with
// stride-33 padding (conflict-free b64 broadcast). dwordx4 gathers: 1 KB/inst.
// MODE 0: store bf16 x1 + lsp[n] = ls*mask^2.  MODE 1: store fp32 out.
// ---------------------------------------------------------------------------
template <int MODE>
__global__ __launch_bounds__(256) void gather_kernel(
    const unsigned short* __restrict__ msg4, const int* __restrict__ adj,
    const float* __restrict__ wgt, const float* __restrict__ mask,
    unsigned short* __restrict__ x1out, float* __restrict__ lsout,
    float* __restrict__ out, int N, int planeHW) {
  __shared__ unsigned long long pairs[64 * 33];
  const int t = threadIdx.x;
  const int lane = t & 63;
  const int wv = t >> 6;
  const int g = lane >> 2;
  const int sub = lane & 3;
  const int nbase = blockIdx.x * 64;

  // Stage (id, w) pairs for this block's 64 nodes (coalesced).
  for (int e = t; e < 64 * 32; e += 256) {
    const int node = e >> 5, k = e & 31;
    const int gn = nbase + node;
    int id = 0;
    float w = 0.f;
    if (gn < N) {
      id = adj[(size_t)gn * 32 + k];
      w = wgt[(size_t)gn * 32 + k];
    }
    pairs[node * 33 + k] = (unsigned long long)(unsigned)id |
        ((unsigned long long)__builtin_bit_cast(unsigned, w) << 32);
  }
  __syncthreads();

  const int mynode = wv * 16 + g;
  const int gnode = nbase + mynode;
  const unsigned long long* mp = pairs + mynode * 33;
  const int suboff = sub * 16;  // byte offset within a 64-B row chunk

  f32x2 acc[16];
#pragma unroll
  for (int i = 0; i < 16; ++i) acc[i] = (f32x2){0.f, 0.f};

#pragma unroll
  for (int p = 0; p < 4; ++p) {
    const char* plane = (const char*)(msg4 + (size_t)p * planeHW);
#pragma unroll 8
    for (int k = 0; k < 32; ++k) {
      const unsigned long long pk = mp[k];
      const unsigned id = (unsigned)pk;
      const float w = __builtin_bit_cast(float, (unsigned)(pk >> 32));
      const uint4 q = *(const uint4*)(plane + ((size_t)id * 64 + suboff));
      const f32x2 w2 = {w, w};
#pragma unroll
      for (int d = 0; d < 4; ++d) {
        const unsigned qd = (&q.x)[d];
        f32x2 v2;
        v2.x = __builtin_bit_cast(float, qd << 16);
        v2.y = __builtin_bit_cast(float, qd & 0xffff0000u);
        acc[p * 4 + d] = __builtin_elementwise_fma(v2, w2, acc[p * 4 + d]);
      }
    }
  }

  // Epilogue: expmap0(c*m)*m, relu, *m. Lane holds 32 cols of its node.
  const int gcl = gnode < N ? gnode : N - 1;
  const float mm = mask[gcl];
  float s2 = 0.f;
#pragma unroll
  for (int i = 0; i < 16; ++i) {
    acc[i].x *= mm;
    acc[i].y *= mm;
    s2 = fmaf(acc[i].x, acc[i].x, s2);
    s2 = fmaf(acc[i].y, acc[i].y, s2);
  }
  s2 += __shfl_xor(s2, 1);
  s2 += __shfl_xor(s2, 2);
  const float nrm = sqrtf(s2);
  const float ncl = fminf(fmaxf(nrm, EPS), MAX_TANH_ARG);
  const float esc = tanhf(ncl) / fmaxf(nrm, EPS) * mm;
  float v[32];
#pragma unroll
  for (int i = 0; i < 16; ++i) {
    v[2 * i] = fmaxf(esc * acc[i].x, 0.f) * mm;
    v[2 * i + 1] = fmaxf(esc * acc[i].y, 0.f) * mm;
  }

  if (MODE == 0) {
    float r2 = 0.f;
#pragma unroll
    for (int i = 0; i < 32; ++i) r2 = fmaf(v[i], v[i], r2);
    r2 += __shfl_xor(r2, 1);
    r2 += __shfl_xor(r2, 2);
    if (gnode < N) {
#pragma unroll
      for (int p = 0; p < 4; ++p) {
        uint4 pk4;
        unsigned* pw = &pk4.x;
#pragma unroll
        for (int d = 0; d < 4; ++d)
          pw[d] = (unsigned)f2bf(v[p * 8 + d * 2]) |
                  ((unsigned)f2bf(v[p * 8 + d * 2 + 1]) << 16);
        *(uint4*)((char*)x1out + (size_t)gnode * 256 + p * 64 + suboff) = pk4;
      }
      if (sub == 0) {
        const float nr = sqrtf(r2);
        const float nc2 = fminf(fmaxf(nr, EPS), 1.0f - PROJ_EPS);
        const float ls = 0.5f * logf((1.f + nc2) / (1.f - nc2)) / fmaxf(nr, EPS);
        lsout[gnode] = ls * mm * mm;  // fold next-layer mask^2
      }
    }
  } else {
    if (gnode < N) {
#pragma unroll
      for (int p = 0; p < 4; ++p) {
        const int cb = p * 32 + sub * 8;
        *(float4*)(out + (size_t)gnode * 128 + cb) =
            make_float4(v[p * 8 + 0], v[p * 8 + 1], v[p * 8 + 2], v[p * 8 + 3]);
        *(float4*)(out + (size_t)gnode * 128 + cb + 4) =
            make_float4(v[p * 8 + 4], v[p * 8 + 5], v[p * 8 + 6], v[p * 8 + 7]);
      }
    }
  }
}

extern "C" void kernel_launch(void* const* d_in, const int* in_sizes, int n_in,
                              void* d_out, int out_size, void* d_ws, size_t ws_size,
                              hipStream_t stream) {
  const float* node = (const float*)d_in[0];        // [N,128] fp32
  const int* adj = (const int*)d_in[1];             // [N,32] int32
  const float* wgt = (const float*)d_in[2];         // [N,32] fp32
  const float* mask = (const float*)d_in[3];        // [N,1] fp32
  const float* mw = (const float*)d_in[4];          // [2,128,128] fp32
  float* out = (float*)d_out;
  const int N = in_sizes[0] / 128;

  const int gb = (N + 63) / 64;           // 64-node chunks (= GEMM tiles)
  const int planeBytes = gb * 64 * 64;    // rows * 64 B per plane
  const int planeHW = planeBytes / 2;

  // workspace: wpack (64 KiB) | lsp (N fp32, 256B-aligned) | msg4 (4 planes)
  char* ws = (char*)d_ws;
  unsigned short* wpack = (unsigned short*)ws;
  float* lsp = (float*)(ws + 65536);
  size_t ls_bytes = ((size_t)N * 4 + 255) & ~(size_t)255;
  unsigned short* msg4 = (unsigned short*)(ws + 65536 + ls_bytes);
  // x1 (bf16, N*128 = half of d_out) lives in d_out; dead before final write
  unsigned short* x1 = (unsigned short*)d_out;

  hipLaunchKernelGGL(pack_w_kernel, dim3(16), dim3(256), 0, stream, mw, wpack);
  hipLaunchKernelGGL((gemm_kernel<0>), dim3(gb), dim3(256), 0, stream,
                     node, (const unsigned short*)nullptr, mask, wpack, msg4, N, planeBytes);
  hipLaunchKernelGGL((gather_kernel<0>), dim3(gb), dim3(256), 0, stream,
                     msg4, adj, wgt, mask, x1, lsp, (float*)nullptr, N, planeHW);
  hipLaunchKernelGGL((gemm_kernel<1>), dim3(gb), dim3(256), 0, stream,
                     (const float*)nullptr, x1, lsp, wpack + 16384, msg4, N, planeBytes);
  hipLaunchKernelGGL((gather_kernel<1>), dim3(gb), dim3(256), 0, stream,
                     msg4, adj, wgt, mask, (unsigned short*)nullptr, (float*)nullptr, out, N, planeHW);
}

// Round 4
// 204.529 us; speedup vs baseline: 1.0598x; 1.0436x over previous
//
#include <hip/hip_runtime.h>

#define EPS 1e-5f
#define PROJ_EPS 1e-5f
#define MAX_TANH_ARG 15.0f

typedef __bf16 bf16x8 __attribute__((ext_vector_type(8)));
typedef float f32x4 __attribute__((ext_vector_type(4)));
typedef float f32x2 __attribute__((ext_vector_type(2)));

__device__ __forceinline__ unsigned short f2bf(float f) {
  unsigned u = __builtin_bit_cast(unsigned, f);
  u += 0x7fffu + ((u >> 16) & 1u);   // round-to-nearest-even
  return (unsigned short)(u >> 16);
}

union BF8 {
  unsigned short u[8];
  bf16x8 v;
  uint4 q;
};

// ---------------------------------------------------------------------------
// Pack W[layer][k][n] (fp32) into bf16 B-fragment order for 16x16x32 MFMA.
// ---------------------------------------------------------------------------
__global__ void pack_w_kernel(const float* __restrict__ W,
                              unsigned short* __restrict__ wpack) {
  int tid = blockIdx.x * blockDim.x + threadIdx.x;  // 0..4095
  if (tid >= 2 * 8 * 4 * 64) return;
  int lane = tid & 63;
  int s = (tid >> 6) & 3;
  int t = (tid >> 8) & 7;
  int layer = tid >> 11;
  int quad = lane >> 4;
  int n = t * 16 + (lane & 15);
  unsigned short* dst = wpack + ((size_t)((layer * 32 + t * 4 + s) * 64 + lane)) * 8;
  const float* src = W + (size_t)layer * 16384;
#pragma unroll
  for (int j = 0; j < 8; ++j) {
    int k = s * 32 + quad * 8 + j;
    dst[j] = f2bf(src[(size_t)k * 128 + n]);
  }
}

// ---------------------------------------------------------------------------
// GEMM0: msg1[planes] = mask^2 * (node_repr @ W0). Wave-local LDS staging:
// each wave coalesced-loads its own 16 fp32 rows (8 KB) into LDS, reads MFMA
// A-frags back (conflict-light), stages bf16 C tile in LDS (union with the
// staging buffer), stores column-tiled planes coalesced.
// ---------------------------------------------------------------------------
__global__ __launch_bounds__(256) void gemm0_kernel(
    const float* __restrict__ xf, const float* __restrict__ mask,
    const unsigned short* __restrict__ wpack, unsigned short* __restrict__ msg1,
    int N, int planeBytes) {
  __shared__ union {
    float xs[4][16][132];            // 33.8 KB fp32 staging (wave-local)
    unsigned short tile[64][136];    // 17.4 KB bf16 C tile
  } sm;
  const int lane = threadIdx.x & 63;
  const int wv = threadIdx.x >> 6;
  const int m = lane & 15;
  const int quad = lane >> 4;
  const int base = blockIdx.x * 64;
  const int wbase = base + wv * 16;

  // Coalesced stage: lane covers 128 B of the wave's 16x512 B row block.
  {
    const int r = lane >> 2;
    const int c = (lane & 3) * 32;
    const int gr = wbase + r;
    const int grc = gr < N ? gr : N - 1;
    const float4* src = (const float4*)(xf + (size_t)grc * 128 + c);
#pragma unroll
    for (int i = 0; i < 8; ++i) *(float4*)&sm.xs[wv][r][c + i * 4] = src[i];
  }
  __syncthreads();

  f32x4 acc[8];
#pragma unroll
  for (int t = 0; t < 8; ++t) acc[t] = (f32x4){0.f, 0.f, 0.f, 0.f};

#pragma unroll
  for (int sk = 0; sk < 4; ++sk) {
    const int k0 = sk * 32 + quad * 8;
    const float4 p0 = *(const float4*)&sm.xs[wv][m][k0];
    const float4 p1 = *(const float4*)&sm.xs[wv][m][k0 + 4];
    BF8 a;
    a.u[0] = f2bf(p0.x); a.u[1] = f2bf(p0.y);
    a.u[2] = f2bf(p0.z); a.u[3] = f2bf(p0.w);
    a.u[4] = f2bf(p1.x); a.u[5] = f2bf(p1.y);
    a.u[6] = f2bf(p1.z); a.u[7] = f2bf(p1.w);
#pragma unroll
    for (int t = 0; t < 8; ++t) {
      BF8 b;
      b.q = *(const uint4*)(wpack + (size_t)((t * 4 + sk) * 64 + lane) * 8);
      acc[t] = __builtin_amdgcn_mfma_f32_16x16x32_bf16(a.v, b.v, acc[t], 0, 0, 0);
    }
  }

  float sc[4];
#pragma unroll
  for (int r = 0; r < 4; ++r) {
    int rr = wbase + quad * 4 + r;
    rr = rr < N ? rr : N - 1;
    const float s = mask[rr];
    sc[r] = s * s;
  }
  __syncthreads();  // xs dead; safe to overwrite as tile

#pragma unroll
  for (int t = 0; t < 8; ++t) {
    const int c = t * 16 + m;
#pragma unroll
    for (int r = 0; r < 4; ++r)
      sm.tile[wv * 16 + quad * 4 + r][c] = f2bf(acc[t][r] * sc[r]);
  }
  // Wave-local coalesced plane writeout (rows wbase..wbase+15).
  const int r16 = lane >> 2;
  const int sub2 = lane & 3;
  const int grow = wbase + r16;
  if (grow < N) {
#pragma unroll
    for (int p = 0; p < 4; ++p) {
      *(uint4*)((char*)msg1 + (size_t)p * planeBytes + (size_t)grow * 64 + sub2 * 16) =
          *(const uint4*)((const char*)&sm.tile[wv * 16 + r16][0] + p * 64 + sub2 * 16);
    }
  }
}

// ---------------------------------------------------------------------------
// FUSED gather0 + GEMM1: per block of 64 nodes:
//   c = sum_k w*msg1[adj]  (4 L2-plane passes, reg accumulators)
//   x1 = relu(expmap0(c*m)*m)*m  -> LDS bf16 tile (wave-local rows)
//   ls = logmap scale(|x1|)*m^2  -> LDS
//   msg2[planes] = ls * (x1 @ W1)  via MFMA, coalesced plane stores.
// Eliminates the standalone GEMM1 dispatch and the x1 global round-trip.
// ---------------------------------------------------------------------------
__global__ __launch_bounds__(256) void fused_kernel(
    const unsigned short* __restrict__ msg1, const int* __restrict__ adj,
    const float* __restrict__ wgt, const float* __restrict__ mask,
    const unsigned short* __restrict__ wpack2, unsigned short* __restrict__ msg2,
    int N, int planeBytes) {
  __shared__ unsigned long long pairs[64 * 33];   // 16.9 KB
  __shared__ unsigned short xtile[64][136];       // 17.4 KB
  __shared__ float lsb[64];
  const int t = threadIdx.x;
  const int lane = t & 63;
  const int wv = t >> 6;
  const int g = lane >> 2;
  const int sub = lane & 3;
  const int nbase = blockIdx.x * 64;

  for (int e = t; e < 64 * 32; e += 256) {
    const int node = e >> 5, k = e & 31;
    const int gn = nbase + node;
    int id = 0;
    float w = 0.f;
    if (gn < N) {
      id = adj[(size_t)gn * 32 + k];
      w = wgt[(size_t)gn * 32 + k];
    }
    pairs[node * 33 + k] = (unsigned long long)(unsigned)id |
        ((unsigned long long)__builtin_bit_cast(unsigned, w) << 32);
  }
  __syncthreads();

  const int mynode = wv * 16 + g;
  const int gnode = nbase + mynode;
  const unsigned long long* mp = pairs + mynode * 33;
  const int suboff = sub * 16;

  f32x2 acc[16];
#pragma unroll
  for (int i = 0; i < 16; ++i) acc[i] = (f32x2){0.f, 0.f};

#pragma unroll
  for (int p = 0; p < 4; ++p) {
    const char* plane = (const char*)msg1 + (size_t)p * planeBytes;
#pragma unroll 8
    for (int k = 0; k < 32; ++k) {
      const unsigned long long pk = mp[k];
      const unsigned id = (unsigned)pk;
      const float w = __builtin_bit_cast(float, (unsigned)(pk >> 32));
      const uint4 q = *(const uint4*)(plane + ((size_t)id * 64 + suboff));
      const f32x2 w2 = {w, w};
#pragma unroll
      for (int d = 0; d < 4; ++d) {
        const unsigned qd = (&q.x)[d];
        f32x2 v2;
        v2.x = __builtin_bit_cast(float, qd << 16);
        v2.y = __builtin_bit_cast(float, qd & 0xffff0000u);
        acc[p * 4 + d] = __builtin_elementwise_fma(v2, w2, acc[p * 4 + d]);
      }
    }
  }

  // expmap0(c*m)*m, relu, *m
  const int gcl = gnode < N ? gnode : N - 1;
  const float mm = mask[gcl];
  float s2 = 0.f;
#pragma unroll
  for (int i = 0; i < 16; ++i) {
    acc[i].x *= mm;
    acc[i].y *= mm;
    s2 = fmaf(acc[i].x, acc[i].x, s2);
    s2 = fmaf(acc[i].y, acc[i].y, s2);
  }
  s2 += __shfl_xor(s2, 1);
  s2 += __shfl_xor(s2, 2);
  const float nrm = sqrtf(s2);
  const float ncl = fminf(fmaxf(nrm, EPS), MAX_TANH_ARG);
  const float esc = tanhf(ncl) / fmaxf(nrm, EPS) * mm;
  float v[32];
  float r2 = 0.f;
#pragma unroll
  for (int i = 0; i < 16; ++i) {
    v[2 * i] = fmaxf(esc * acc[i].x, 0.f) * mm;
    v[2 * i + 1] = fmaxf(esc * acc[i].y, 0.f) * mm;
    r2 = fmaf(v[2 * i], v[2 * i], r2);
    r2 = fmaf(v[2 * i + 1], v[2 * i + 1], r2);
  }
  r2 += __shfl_xor(r2, 1);
  r2 += __shfl_xor(r2, 2);

  // Stage x1 (bf16) into LDS tile rows (wave-local) + log-map scale.
#pragma unroll
  for (int p = 0; p < 4; ++p) {
    uint4 pk4;
    unsigned* pw = &pk4.x;
#pragma unroll
    for (int d = 0; d < 4; ++d)
      pw[d] = (unsigned)f2bf(v[p * 8 + d * 2]) |
              ((unsigned)f2bf(v[p * 8 + d * 2 + 1]) << 16);
    *(uint4*)((char*)&xtile[mynode][0] + p * 64 + suboff) = pk4;
  }
  if (sub == 0) {
    const float nr = sqrtf(r2);
    const float nc2 = fminf(fmaxf(nr, EPS), 1.0f - PROJ_EPS);
    const float ls = 0.5f * logf((1.f + nc2) / (1.f - nc2)) / fmaxf(nr, EPS);
    lsb[mynode] = ls * mm * mm;  // fold layer-2 mask^2
  }
  __syncthreads();

  // GEMM1 phase: A = xtile rows (wave-local), B = wpack2, C = ls * (x1@W1).
  const int m = lane & 15;
  const int quad = lane >> 4;
  f32x4 accg[8];
#pragma unroll
  for (int tt = 0; tt < 8; ++tt) accg[tt] = (f32x4){0.f, 0.f, 0.f, 0.f};
#pragma unroll
  for (int sk = 0; sk < 4; ++sk) {
    const int k0 = sk * 32 + quad * 8;  // shorts
    BF8 a;
    a.q = *(const uint4*)((const char*)&xtile[wv * 16 + m][0] + k0 * 2);
#pragma unroll
    for (int tt = 0; tt < 8; ++tt) {
      BF8 b;
      b.q = *(const uint4*)(wpack2 + (size_t)((tt * 4 + sk) * 64 + lane) * 8);
      accg[tt] = __builtin_amdgcn_mfma_f32_16x16x32_bf16(a.v, b.v, accg[tt], 0, 0, 0);
    }
  }
  float sc[4];
#pragma unroll
  for (int r = 0; r < 4; ++r) sc[r] = lsb[wv * 16 + quad * 4 + r];
  // Overwrite own tile rows with scaled bf16 C (wave-local, A already read).
#pragma unroll
  for (int tt = 0; tt < 8; ++tt) {
    const int c = tt * 16 + m;
#pragma unroll
    for (int r = 0; r < 4; ++r)
      xtile[wv * 16 + quad * 4 + r][c] = f2bf(accg[tt][r] * sc[r]);
  }
  // Wave-local coalesced plane writeout.
  const int r16 = lane >> 2;
  const int sub2 = lane & 3;
  const int grow = nbase + wv * 16 + r16;
  if (grow < N) {
#pragma unroll
    for (int p = 0; p < 4; ++p) {
      *(uint4*)((char*)msg2 + (size_t)p * planeBytes + (size_t)grow * 64 + sub2 * 16) =
          *(const uint4*)((const char*)&xtile[wv * 16 + r16][0] + p * 64 + sub2 * 16);
    }
  }
}

// ---------------------------------------------------------------------------
// Final gather: out = relu(expmap0(sum_k w*msg2[adj] * m)*m)*m, fp32 stores.
// ---------------------------------------------------------------------------
__global__ __launch_bounds__(256) void gather_out_kernel(
    const unsigned short* __restrict__ msg2, const int* __restrict__ adj,
    const float* __restrict__ wgt, const float* __restrict__ mask,
    float* __restrict__ out, int N, int planeBytes) {
  __shared__ unsigned long long pairs[64 * 33];
  const int t = threadIdx.x;
  const int lane = t & 63;
  const int wv = t >> 6;
  const int g = lane >> 2;
  const int sub = lane & 3;
  const int nbase = blockIdx.x * 64;

  for (int e = t; e < 64 * 32; e += 256) {
    const int node = e >> 5, k = e & 31;
    const int gn = nbase + node;
    int id = 0;
    float w = 0.f;
    if (gn < N) {
      id = adj[(size_t)gn * 32 + k];
      w = wgt[(size_t)gn * 32 + k];
    }
    pairs[node * 33 + k] = (unsigned long long)(unsigned)id |
        ((unsigned long long)__builtin_bit_cast(unsigned, w) << 32);
  }
  __syncthreads();

  const int mynode = wv * 16 + g;
  const int gnode = nbase + mynode;
  const unsigned long long* mp = pairs + mynode * 33;
  const int suboff = sub * 16;

  f32x2 acc[16];
#pragma unroll
  for (int i = 0; i < 16; ++i) acc[i] = (f32x2){0.f, 0.f};

#pragma unroll
  for (int p = 0; p < 4; ++p) {
    const char* plane = (const char*)msg2 + (size_t)p * planeBytes;
#pragma unroll 8
    for (int k = 0; k < 32; ++k) {
      const unsigned long long pk = mp[k];
      const unsigned id = (unsigned)pk;
      const float w = __builtin_bit_cast(float, (unsigned)(pk >> 32));
      const uint4 q = *(const uint4*)(plane + ((size_t)id * 64 + suboff));
      const f32x2 w2 = {w, w};
#pragma unroll
      for (int d = 0; d < 4; ++d) {
        const unsigned qd = (&q.x)[d];
        f32x2 v2;
        v2.x = __builtin_bit_cast(float, qd << 16);
        v2.y = __builtin_bit_cast(float, qd & 0xffff0000u);
        acc[p * 4 + d] = __builtin_elementwise_fma(v2, w2, acc[p * 4 + d]);
      }
    }
  }

  const int gcl = gnode < N ? gnode : N - 1;
  const float mm = mask[gcl];
  float s2 = 0.f;
#pragma unroll
  for (int i = 0; i < 16; ++i) {
    acc[i].x *= mm;
    acc[i].y *= mm;
    s2 = fmaf(acc[i].x, acc[i].x, s2);
    s2 = fmaf(acc[i].y, acc[i].y, s2);
  }
  s2 += __shfl_xor(s2, 1);
  s2 += __shfl_xor(s2, 2);
  const float nrm = sqrtf(s2);
  const float ncl = fminf(fmaxf(nrm, EPS), MAX_TANH_ARG);
  const float esc = tanhf(ncl) / fmaxf(nrm, EPS) * mm;
  if (gnode < N) {
#pragma unroll
    for (int p = 0; p < 4; ++p) {
      float4 o0, o1;
      o0.x = fmaxf(esc * acc[p * 4 + 0].x, 0.f) * mm;
      o0.y = fmaxf(esc * acc[p * 4 + 0].y, 0.f) * mm;
      o0.z = fmaxf(esc * acc[p * 4 + 1].x, 0.f) * mm;
      o0.w = fmaxf(esc * acc[p * 4 + 1].y, 0.f) * mm;
      o1.x = fmaxf(esc * acc[p * 4 + 2].x, 0.f) * mm;
      o1.y = fmaxf(esc * acc[p * 4 + 2].y, 0.f) * mm;
      o1.z = fmaxf(esc * acc[p * 4 + 3].x, 0.f) * mm;
      o1.w = fmaxf(esc * acc[p * 4 + 3].y, 0.f) * mm;
      const int cb = p * 32 + sub * 8;
      *(float4*)(out + (size_t)gnode * 128 + cb) = o0;
      *(float4*)(out + (size_t)gnode * 128 + cb + 4) = o1;
    }
  }
}

extern "C" void kernel_launch(void* const* d_in, const int* in_sizes, int n_in,
                              void* d_out, int out_size, void* d_ws, size_t ws_size,
                              hipStream_t stream) {
  const float* node = (const float*)d_in[0];        // [N,128] fp32
  const int* adj = (const int*)d_in[1];             // [N,32] int32
  const float* wgt = (const float*)d_in[2];         // [N,32] fp32
  const float* mask = (const float*)d_in[3];        // [N,1] fp32
  const float* mw = (const float*)d_in[4];          // [2,128,128] fp32
  float* out = (float*)d_out;
  const int N = in_sizes[0] / 128;

  const int gb = (N + 63) / 64;
  const int planeBytes = gb * 64 * 64;  // bytes per 32-col bf16 plane

  // msg1 planes live in d_out (4*planeBytes = 12.8 MB <= 25.6 MB, dead
  // before gather_out writes); msg2 planes live in ws after wpack.
  unsigned short* wpack = (unsigned short*)d_ws;
  unsigned short* msg2 = (unsigned short*)((char*)d_ws + 65536);
  unsigned short* msg1 = (unsigned short*)d_out;

  hipLaunchKernelGGL(pack_w_kernel, dim3(16), dim3(256), 0, stream, mw, wpack);
  hipLaunchKernelGGL(gemm0_kernel, dim3(gb), dim3(256), 0, stream,
                     node, mask, wpack, msg1, N, planeBytes);
  hipLaunchKernelGGL(fused_kernel, dim3(gb), dim3(256), 0, stream,
                     msg1, adj, wgt, mask, wpack + 16384, msg2, N, planeBytes);
  hipLaunchKernelGGL(gather_out_kernel, dim3(gb), dim3(256), 0, stream,
                     msg2, adj, wgt, mask, out, N, planeBytes);
}